// Round 4
// baseline (61.168 us; speedup 1.0000x reference)
//
#include <hip/hip_runtime.h>
#include <stdint.h>

#define BATCH 8192
#define DIM   1024
#define BM 128
#define BN 128
#define BK 64
#define NT (DIM / BK)   // 16

typedef __attribute__((ext_vector_type(4))) float f32x4;
typedef __attribute__((ext_vector_type(8))) short bf16x8;
typedef __attribute__((ext_vector_type(4))) unsigned short u16x4;
typedef __attribute__((ext_vector_type(8))) unsigned short u16x8;

#define AS1(p) ((const __attribute__((address_space(1))) void*)(p))
#define AS3(p) ((__attribute__((address_space(3))) void*)(p))

__device__ __forceinline__ unsigned short f2bf(float f) {
    union { float f; unsigned int u; } v; v.f = f;
    unsigned int u = v.u;
    u += 0x7fffu + ((u >> 16) & 1u);   // round-to-nearest-even
    return (unsigned short)(u >> 16);
}

__device__ __forceinline__ float sigma_f(float x) {
    float x2 = x * x;
    return x2 * __builtin_amdgcn_rcpf(1.0f + x2);
}

// ---------------------------------------------------------------------------
// Kernel 1: convert A (f32 [D][D]) to bf16
// ---------------------------------------------------------------------------
__global__ __launch_bounds__(256) void convA_kernel(
    const float* __restrict__ A, unsigned short* __restrict__ Ab)
{
    int idx = blockIdx.x * 256 + threadIdx.x;    // vec4 index, grid exact
    f32x4 av = ((const f32x4*)A)[idx];
    u16x4 ab;
#pragma unroll
    for (int i = 0; i < 4; ++i) ab[i] = f2bf(av[i]);
    ((u16x4*)Ab)[idx] = ab;
}

// ---------------------------------------------------------------------------
// Kernel 2: fully fused, pipelined, with PINNED issue-early prefetch.
//   Per K-step: {issue x loads (4), issue B global_load_lds (2)} ->
//   sched_barrier(0) -> ds_read+MFMA(t) -> sched_barrier(0) ->
//   sigma(x)+ds_write(t+1) -> __syncthreads.
//   x issued BEFORE B so the compiler can wait vmcnt(2) for sigma while
//   B's global_load_lds stay in flight until the barrier drain.
// ---------------------------------------------------------------------------
__global__ __launch_bounds__(512, 4) void fused_kernel(
    const float* __restrict__ x, const float* __restrict__ ex,
    const float* __restrict__ W, const float* __restrict__ tgt,
    const unsigned short* __restrict__ Ab,
    float* __restrict__ out0, float* __restrict__ out1,
    float* __restrict__ out2)
{
    __shared__ __align__(16) char lds[65536];    // 2 x (As 16K | Bs 16K); epilogue: C f32[128][128]

    // ---- XCD-aware block swizzle
    const int p    = blockIdx.x;
    const int xcd  = p & 7;
    const int slot = p >> 3;                     // 0..63 per XCD
    const int bm   = xcd * 8 + (slot >> 3);
    const int bn   = slot & 7;

    const int tid  = threadIdx.x;
    const int lane = tid & 63;
    const int wid  = tid >> 6;                   // 0..7
    const int wr   = wid >> 2;                   // 0..1
    const int wc   = wid & 3;                    // 0..3

    // ---- B staging (global_load_lds, source carries the XOR swizzle; LDS linear)
    const int swz = (((lane & 7) ^ (lane >> 3)) << 4);
    const char* gB = (const char*)Ab +
        ((size_t)(bn * BN + (lane >> 3)) * DIM) * 2 + swz;

    // ---- A staging (reg-staged sigma): thread -> rows r0, r0+64; col grp g
    const int r0 = tid >> 3;                     // 0..63
    const int g  = tid & 7;                      // 0..7 (8 f32 each)
    const float* gx = x + (size_t)(bm * BM + r0) * DIM + g * 8;
    const int wAoff = (g * 16) ^ ((r0 & 7) << 4);

    // ---- fragment read constants
    const int rd_sw = (lane & 7) << 4;
    const int cb0   = (lane >> 4) << 4;

    f32x4 acc[4][2];
#pragma unroll
    for (int mi = 0; mi < 4; ++mi)
#pragma unroll
        for (int ni = 0; ni < 2; ++ni)
            acc[mi][ni] = f32x4{0.f, 0.f, 0.f, 0.f};

    // ---------------- prologue: stage tile 0 into buffer 0
    {
        f32x4 xa[2][2];
#pragma unroll
        for (int s = 0; s < 2; ++s) {
            xa[s][0] = *(const f32x4*)(gx + (size_t)s * 64 * DIM);
            xa[s][1] = *(const f32x4*)(gx + (size_t)s * 64 * DIM + 4);
        }
        char* dstB = lds + 16384;
#pragma unroll
        for (int j = 0; j < 2; ++j)
            __builtin_amdgcn_global_load_lds(
                AS1(gB + (size_t)(j * 64 + wid * 8) * (DIM * 2)),
                AS3(dstB + (j * 64 + wid * 8) * 128), 16, 0, 0);
#pragma unroll
        for (int s = 0; s < 2; ++s) {
            u16x8 sb;
#pragma unroll
            for (int i = 0; i < 4; ++i) {
                sb[i]     = f2bf(sigma_f(xa[s][0][i]));
                sb[i + 4] = f2bf(sigma_f(xa[s][1][i]));
            }
            *(u16x8*)(lds + (s * 64 + r0) * 128 + wAoff) = sb;
        }
    }
    __syncthreads();

    // ---------------- main K loop: one barrier per step, pinned prefetch
    for (int t = 0; t < NT; ++t) {
        const int cur = t & 1;
        f32x4 xa[2][2];
        if (t + 1 < NT) {
            const int k0n = (t + 1) * BK;
            // x loads FIRST (oldest in vmcnt queue -> waitable with vmcnt(2))
#pragma unroll
            for (int s = 0; s < 2; ++s) {
                xa[s][0] = *(const f32x4*)(gx + (size_t)s * 64 * DIM + k0n);
                xa[s][1] = *(const f32x4*)(gx + (size_t)s * 64 * DIM + k0n + 4);
            }
            char* dstB = lds + (cur ^ 1) * 32768 + 16384;
#pragma unroll
            for (int j = 0; j < 2; ++j)
                __builtin_amdgcn_global_load_lds(
                    AS1(gB + (size_t)(j * 64 + wid * 8) * (DIM * 2) + (size_t)k0n * 2),
                    AS3(dstB + (j * 64 + wid * 8) * 128), 16, 0, 0);
        }
        __builtin_amdgcn_sched_barrier(0);   // pin: loads stay issued-early

        const char* As_ = lds + cur * 32768;
        const char* Bs_ = As_ + 16384;
#pragma unroll
        for (int kk = 0; kk < 2; ++kk) {
            bf16x8 af[4], bfr[2];
#pragma unroll
            for (int mi = 0; mi < 4; ++mi)
                af[mi] = *(const bf16x8*)(As_ + (wr * 64 + mi * 16 + (lane & 15)) * 128 +
                                          ((cb0 + kk * 64) ^ rd_sw));
#pragma unroll
            for (int ni = 0; ni < 2; ++ni)
                bfr[ni] = *(const bf16x8*)(Bs_ + (wc * 32 + ni * 16 + (lane & 15)) * 128 +
                                           ((cb0 + kk * 64) ^ rd_sw));
#pragma unroll
            for (int mi = 0; mi < 4; ++mi)
#pragma unroll
                for (int ni = 0; ni < 2; ++ni)
                    acc[mi][ni] = __builtin_amdgcn_mfma_f32_16x16x32_bf16(
                        af[mi], bfr[ni], acc[mi][ni], 0, 0, 0);
        }
        __builtin_amdgcn_sched_barrier(0);   // MFMA phase complete before sigma

        if (t + 1 < NT) {
            char* dstA = lds + (cur ^ 1) * 32768;
#pragma unroll
            for (int s = 0; s < 2; ++s) {
                u16x8 sb;
#pragma unroll
                for (int i = 0; i < 4; ++i) {
                    sb[i]     = f2bf(sigma_f(xa[s][0][i]));
                    sb[i + 4] = f2bf(sigma_f(xa[s][1][i]));
                }
                *(u16x8*)(dstA + (s * 64 + r0) * 128 + wAoff) = sb;
            }
        }
        __syncthreads();
    }

    // ---------------- epilogue: acc -> LDS C-tile (swizzled 16B groups)
#pragma unroll
    for (int mi = 0; mi < 4; ++mi)
#pragma unroll
        for (int ni = 0; ni < 2; ++ni) {
            const int row_ = wr * 64 + mi * 16 + ((lane >> 4) << 2);
            const int colb = (wc * 32 + ni * 16 + (lane & 15)) * 4;
#pragma unroll
            for (int r = 0; r < 4; ++r) {
                const int rr = row_ + r;
                *(float*)(lds + rr * 512 + (colb ^ (((rr >> 2) & 7) << 4))) = acc[mi][ni][r];
            }
        }
    __syncthreads();

    // ---- streaming pass: row-major, fully vectorized
#pragma unroll
    for (int i = 0; i < 8; ++i) {
        const int ci  = tid + i * 512;
        const int row = ci >> 5;                 // 0..127
        const int cv  = ci & 31;                 // f32x4 col index
        f32x4 c = *(const f32x4*)(lds + row * 512 + ((cv * 16) ^ (((row >> 2) & 7) << 4)));
        const size_t v4 = (size_t)(bm * BM + row) * (DIM / 4) + bn * (BN / 4) + cv;
        f32x4 xv = ((const f32x4*)x)[v4];
        f32x4 ev = ((const f32x4*)ex)[v4];
        f32x4 wv = ((const f32x4*)W)[v4];
        f32x4 tv = ((const f32x4*)tgt)[bn * (BN / 4) + cv];
        f32x4 o0;
#pragma unroll
        for (int e = 0; e < 4; ++e) {
            float xi = xv[e], ti = tv[e];
            float ba = ti * ti * __builtin_amdgcn_rcpf(1.0f + ti * ti);
            float u  = -(wv[e] * (xi + ev[e] - ti)) * ba;
            float s  = sigma_f(xi);
            o0[e] = -xi + u * s + c[e];
        }
        ((f32x4*)out0)[v4] = o0;
        ((f32x4*)out1)[v4] = -o0;
        ((f32x4*)out2)[v4] = f32x4{0.f, 0.f, 0.f, 0.f};
    }
}

// ---------------------------------------------------------------------------
extern "C" void kernel_launch(void* const* d_in, const int* in_sizes, int n_in,
                              void* d_out, int out_size, void* d_ws, size_t ws_size,
                              hipStream_t stream)
{
    const float* x   = (const float*)d_in[0];
    const float* ex  = (const float*)d_in[1];
    const float* W   = (const float*)d_in[2];
    const float* A   = (const float*)d_in[3];
    const float* tgt = (const float*)d_in[4];

    float* out0 = (float*)d_out;
    float* out1 = out0 + (size_t)BATCH * DIM;
    float* out2 = out1 + (size_t)BATCH * DIM;

    unsigned short* Abf = (unsigned short*)d_ws;   // 2 MiB

    convA_kernel<<<DIM * DIM / 4 / 256, 256, 0, stream>>>(A, Abf);
    fused_kernel<<<(BATCH / BM) * (DIM / BN), 512, 0, stream>>>(
        x, ex, W, tgt, Abf, out0, out1, out2);
}

// Round 5
// 59.381 us; speedup vs baseline: 1.0301x; 1.0301x over previous
//
#include <hip/hip_runtime.h>
#include <hip/hip_bf16.h>
#include <stdint.h>

#define BATCH 8192
#define DIM   1024
#define BM 128
#define BN 128
#define BK 64
#define NT (DIM / BK)   // 16

typedef __attribute__((ext_vector_type(4))) float f32x4;
typedef __attribute__((ext_vector_type(8))) short bf16x8;
typedef __attribute__((ext_vector_type(4))) unsigned short u16x4;
typedef __attribute__((ext_vector_type(8))) unsigned short u16x8;

#define AS1(p) ((const __attribute__((address_space(1))) void*)(p))
#define AS3(p) ((__attribute__((address_space(3))) void*)(p))

__device__ __forceinline__ unsigned short f2bf(float f) {
    union { __hip_bfloat16 h; unsigned short u; } v;
    v.h = __hip_bfloat16(f);       // compiler emits v_cvt_pk_bf16_f32 pairs
    return v.u;
}

__device__ __forceinline__ float sigma_f(float x) {
    float x2 = x * x;
    return x2 * __builtin_amdgcn_rcpf(1.0f + x2);
}

// ---------------------------------------------------------------------------
// Kernel 1: convert A (f32 [D][D]) to bf16
// ---------------------------------------------------------------------------
__global__ __launch_bounds__(256) void convA_kernel(
    const float* __restrict__ A, unsigned short* __restrict__ Ab)
{
    int idx = blockIdx.x * 256 + threadIdx.x;    // vec4 index, grid exact
    f32x4 av = ((const f32x4*)A)[idx];
    u16x4 ab;
#pragma unroll
    for (int i = 0; i < 4; ++i) ab[i] = f2bf(av[i]);
    ((u16x4*)Ab)[idx] = ab;
}

// ---------------------------------------------------------------------------
// Kernel 2: fused, 4-wave blocks, wave grid 2x2 (64x64/wave, acc[4][4]).
//   LDS-read amplification (2+2) vs (4+2) of the 8-wave 2x4 grid.
//   Double-buffered 2x32 KiB staging; epilogue C-tile reuses the 64 KiB.
//   Per K-step: {x loads, B global_load_lds} -> sched_barrier ->
//   ds_read+MFMA -> sched_barrier -> sigma+cvt_pk+ds_write -> barrier.
// ---------------------------------------------------------------------------
__global__ __launch_bounds__(256, 2) void fused_kernel(
    const float* __restrict__ x, const float* __restrict__ ex,
    const float* __restrict__ W, const float* __restrict__ tgt,
    const unsigned short* __restrict__ Ab,
    float* __restrict__ out0, float* __restrict__ out1,
    float* __restrict__ out2)
{
    __shared__ __align__(16) char lds[65536];    // 2 x (As 16K | Bs 16K); epilogue: C f32[128][128]

    // ---- XCD-aware block swizzle
    const int p    = blockIdx.x;
    const int xcd  = p & 7;
    const int slot = p >> 3;                     // 0..63 per XCD
    const int bm   = xcd * 8 + (slot >> 3);      // 0..63
    const int bn   = slot & 7;

    const int tid  = threadIdx.x;
    const int lane = tid & 63;
    const int wid  = tid >> 6;                   // 0..3
    const int wr   = wid >> 1;                   // 0..1
    const int wc   = wid & 1;                    // 0..1

    // ---- B staging (global_load_lds, source carries the XOR swizzle; LDS linear)
    const int swz = (((lane & 7) ^ (lane >> 3)) << 4);
    const char* gB = (const char*)Ab +
        ((size_t)(bn * BN + (lane >> 3)) * DIM) * 2 + swz;

    // ---- A staging (reg-staged sigma): thread -> rows r0+32s (s=0..3), col grp g
    const int r0 = tid >> 3;                     // 0..31
    const int g  = tid & 7;                      // 0..7 (8 f32 each)
    const float* gx = x + (size_t)(bm * BM + r0) * DIM + g * 8;
    const int wAoff = (g * 16) ^ ((r0 & 7) << 4);

    // ---- fragment read constants
    const int rd_sw = (lane & 7) << 4;
    const int cb0   = (lane >> 4) << 4;

    f32x4 acc[4][4];
#pragma unroll
    for (int mi = 0; mi < 4; ++mi)
#pragma unroll
        for (int ni = 0; ni < 4; ++ni)
            acc[mi][ni] = f32x4{0.f, 0.f, 0.f, 0.f};

    // ---------------- prologue: stage tile 0 into buffer 0
    {
        f32x4 xa[4][2];
#pragma unroll
        for (int s = 0; s < 4; ++s) {
            xa[s][0] = *(const f32x4*)(gx + (size_t)s * 32 * DIM);
            xa[s][1] = *(const f32x4*)(gx + (size_t)s * 32 * DIM + 4);
        }
        char* dstB = lds + 16384;
#pragma unroll
        for (int j = 0; j < 4; ++j)
            __builtin_amdgcn_global_load_lds(
                AS1(gB + (size_t)(j * 32 + wid * 8) * (DIM * 2)),
                AS3(dstB + (j * 32 + wid * 8) * 128), 16, 0, 0);
#pragma unroll
        for (int s = 0; s < 4; ++s) {
            u16x8 sb;
#pragma unroll
            for (int i = 0; i < 4; ++i) {
                sb[i]     = f2bf(sigma_f(xa[s][0][i]));
                sb[i + 4] = f2bf(sigma_f(xa[s][1][i]));
            }
            *(u16x8*)(lds + (s * 32 + r0) * 128 + wAoff) = sb;
        }
    }
    __syncthreads();

    // ---------------- main K loop: one barrier per step, pinned prefetch
    for (int t = 0; t < NT; ++t) {
        const int cur = t & 1;
        f32x4 xa[4][2];
        if (t + 1 < NT) {
            const int k0n = (t + 1) * BK;
            // x loads FIRST (oldest in vmcnt queue)
#pragma unroll
            for (int s = 0; s < 4; ++s) {
                xa[s][0] = *(const f32x4*)(gx + (size_t)s * 32 * DIM + k0n);
                xa[s][1] = *(const f32x4*)(gx + (size_t)s * 32 * DIM + k0n + 4);
            }
            char* dstB = lds + (cur ^ 1) * 32768 + 16384;
#pragma unroll
            for (int j = 0; j < 4; ++j)
                __builtin_amdgcn_global_load_lds(
                    AS1(gB + (size_t)(j * 32 + wid * 8) * (DIM * 2) + (size_t)k0n * 2),
                    AS3(dstB + (j * 32 + wid * 8) * 128), 16, 0, 0);
        }
        __builtin_amdgcn_sched_barrier(0);   // pin: loads stay issued-early

        const char* As_ = lds + cur * 32768;
        const char* Bs_ = As_ + 16384;
#pragma unroll
        for (int kk = 0; kk < 2; ++kk) {
            bf16x8 af[4], bfr[4];
#pragma unroll
            for (int mi = 0; mi < 4; ++mi)
                af[mi] = *(const bf16x8*)(As_ + (wr * 64 + mi * 16 + (lane & 15)) * 128 +
                                          ((cb0 + kk * 64) ^ rd_sw));
#pragma unroll
            for (int ni = 0; ni < 4; ++ni)
                bfr[ni] = *(const bf16x8*)(Bs_ + (wc * 64 + ni * 16 + (lane & 15)) * 128 +
                                           ((cb0 + kk * 64) ^ rd_sw));
#pragma unroll
            for (int mi = 0; mi < 4; ++mi)
#pragma unroll
                for (int ni = 0; ni < 4; ++ni)
                    acc[mi][ni] = __builtin_amdgcn_mfma_f32_16x16x32_bf16(
                        af[mi], bfr[ni], acc[mi][ni], 0, 0, 0);
        }
        __builtin_amdgcn_sched_barrier(0);   // MFMA phase complete before sigma

        if (t + 1 < NT) {
            char* dstA = lds + (cur ^ 1) * 32768;
#pragma unroll
            for (int s = 0; s < 4; ++s) {
                u16x8 sb;
#pragma unroll
                for (int i = 0; i < 4; ++i) {
                    sb[i]     = f2bf(sigma_f(xa[s][0][i]));
                    sb[i + 4] = f2bf(sigma_f(xa[s][1][i]));
                }
                *(u16x8*)(dstA + (s * 32 + r0) * 128 + wAoff) = sb;
            }
        }
        __syncthreads();
    }

    // ---------------- epilogue: acc -> LDS C-tile (swizzled 16B groups)
#pragma unroll
    for (int mi = 0; mi < 4; ++mi)
#pragma unroll
        for (int ni = 0; ni < 4; ++ni) {
            const int row_ = wr * 64 + mi * 16 + ((lane >> 4) << 2);
            const int colb = (wc * 64 + ni * 16 + (lane & 15)) * 4;
#pragma unroll
            for (int r = 0; r < 4; ++r) {
                const int rr = row_ + r;
                *(float*)(lds + rr * 512 + (colb ^ (((rr >> 2) & 7) << 4))) = acc[mi][ni][r];
            }
        }
    __syncthreads();

    // ---- streaming pass: row-major, fully vectorized
#pragma unroll
    for (int i = 0; i < 16; ++i) {
        const int ci  = tid + i * 256;
        const int row = ci >> 5;                 // 0..127
        const int cv  = ci & 31;                 // f32x4 col index
        f32x4 c = *(const f32x4*)(lds + row * 512 + ((cv * 16) ^ (((row >> 2) & 7) << 4)));
        const size_t v4 = (size_t)(bm * BM + row) * (DIM / 4) + bn * (BN / 4) + cv;
        f32x4 xv = ((const f32x4*)x)[v4];
        f32x4 ev = ((const f32x4*)ex)[v4];
        f32x4 wv = ((const f32x4*)W)[v4];
        f32x4 tv = ((const f32x4*)tgt)[bn * (BN / 4) + cv];
        f32x4 o0;
#pragma unroll
        for (int e = 0; e < 4; ++e) {
            float xi = xv[e], ti = tv[e];
            float ba = ti * ti * __builtin_amdgcn_rcpf(1.0f + ti * ti);
            float u  = -(wv[e] * (xi + ev[e] - ti)) * ba;
            float s  = sigma_f(xi);
            o0[e] = -xi + u * s + c[e];
        }
        ((f32x4*)out0)[v4] = o0;
        ((f32x4*)out1)[v4] = -o0;
        ((f32x4*)out2)[v4] = f32x4{0.f, 0.f, 0.f, 0.f};
    }
}

// ---------------------------------------------------------------------------
extern "C" void kernel_launch(void* const* d_in, const int* in_sizes, int n_in,
                              void* d_out, int out_size, void* d_ws, size_t ws_size,
                              hipStream_t stream)
{
    const float* x   = (const float*)d_in[0];
    const float* ex  = (const float*)d_in[1];
    const float* W   = (const float*)d_in[2];
    const float* A   = (const float*)d_in[3];
    const float* tgt = (const float*)d_in[4];

    float* out0 = (float*)d_out;
    float* out1 = out0 + (size_t)BATCH * DIM;
    float* out2 = out1 + (size_t)BATCH * DIM;

    unsigned short* Abf = (unsigned short*)d_ws;   // 2 MiB

    convA_kernel<<<DIM * DIM / 4 / 256, 256, 0, stream>>>(A, Abf);
    fused_kernel<<<(BATCH / BM) * (DIM / BN), 256, 0, stream>>>(
        x, ex, W, tgt, Abf, out0, out1, out2);
}